// Round 7
// baseline (315.267 us; speedup 1.0000x reference)
//
#include <hip/hip_runtime.h>

// AdditiveRecursiveNN: full 12-level binary tree of 32x32 matmuls + head in ONE
// kernel launch. 256 blocks x 512 threads; three phases linked by device-scope
// flag handshakes in d_ws (kernel boundaries replaced by atomics):
//   P1 (all 256 blocks): leaves + levels n=2048,1024,512,256 in LDS -> node256[b]
//   P2 (blocks 0..15):   levels n=128,64,32,16 -> node16[b]
//   P3 (block 0):        levels n=8,4,2,1 + head -> out[2] (f32: pred, loss)
// Cross-XCD correctness: producers drain stores (__syncthreads waits vmcnt),
// then RELEASE/AGENT flag store (writes back producer L2); consumers spin with
// ACQUIRE/AGENT and read node data with RELAXED/AGENT loads (bypass consumer
// L2, which may hold stale 0xAA poison lines from the harness fill).
// Flags: re-poisoned to 0xAA every call => never spuriously MAGIC, no init.
// (Rounds 5 and 6 were GPUAcquisitionTimeouts — this source is the unchanged
// round-5 kernel, resubmitted to get its first hardware measurement.)

#define NS 1056  // per-node LDS stride: 32 rows x (32+1) padded cols
#define MAGICV 0x5EED5EEDu

__device__ __forceinline__ float frelu(float x) { return x > 0.f ? x : 0.f; }

__device__ __forceinline__ float agload(const float* p) {
  return __hip_atomic_load(p, __ATOMIC_RELAXED, __HIP_MEMORY_SCOPE_AGENT);
}

// 4 tree levels in LDS for one block: 8 -> 4 -> 2 -> 1 nodes. A = inputs
// (padded [32][33] per node), B = outputs. offs[L] + nl*b + node indexes
// internal_ids. Ends with B[0] = block's root node, LDS-synced.
__device__ __forceinline__ void run4(const float* __restrict__ emb,
                                     const float* __restrict__ bias,
                                     const int* __restrict__ internal_ids,
                                     int b, const int* offs, float* A, float* B) {
  const int t = threadIdx.x;
#pragma unroll
  for (int L = 0; L < 4; ++L) {
    const int nl = 8 >> L;
    const int tpn = 512 / nl;        // threads per node
    const int node = t / tpn;
    const int g = t % tpn;
    const int k = g & 31;            // output column (W row)
    const int rb = g >> 5;           // row block
    const int rpt = 1024 / tpn;      // rows per thread
    const int wid = internal_ids[offs[L] + nl * b + node];

    float w[32];
    const float4* Wr = (const float4*)(emb + (size_t)wid * 1024 + k * 32);
#pragma unroll
    for (int q = 0; q < 8; ++q) {
      const float4 v = Wr[q];
      w[4 * q] = v.x; w[4 * q + 1] = v.y; w[4 * q + 2] = v.z; w[4 * q + 3] = v.w;
    }
    const float bk = bias[(size_t)wid * 32 + k];

    const float* ip = A + node * NS;
    float* op = B + node * NS;
    const int i0 = rb * rpt;
#pragma unroll
    for (int ii = 0; ii < rpt; ++ii) {
      const int i = i0 + ii;
      float acc = bk;
#pragma unroll
      for (int j = 0; j < 32; ++j) acc += ip[i * 33 + j] * w[j];
      op[i * 33 + k] = frelu(acc);
    }
    __syncthreads();

    if (L < 3) {  // next level inputs: A[m] = B[2m] + B[2m+1]
      const int nl2 = nl >> 1;
      for (int u = t; u < nl2 * 1024; u += 512) {
        const int m = u >> 10, e = u & 1023;
        const int idx = (e >> 5) * 33 + (e & 31);
        A[m * NS + idx] = B[2 * m * NS + idx] + B[(2 * m + 1) * NS + idx];
      }
      __syncthreads();
    }
  }
}

__global__ __launch_bounds__(512) void tree_kernel(
    const float* __restrict__ emb, const float* __restrict__ bias,
    const float* __restrict__ projW, const float* __restrict__ projb,
    const int* __restrict__ leaf_ids, const int* __restrict__ internal_ids,
    const int* __restrict__ label_ptr, float* __restrict__ node256,
    float* __restrict__ node16, unsigned int* __restrict__ flag1,
    unsigned int* __restrict__ flag2, float* __restrict__ out) {
  __shared__ float A[8 * NS];
  __shared__ float B[8 * NS];
  __shared__ float red[16];

  const int b = blockIdx.x;
  const int t = threadIdx.x;

  // ================= Phase 1: all 256 blocks =================
  {  // stage: A[g] = relu(emb[leaf0]) + relu(emb[leaf1]) for 8 node-pairs
    const int g = t >> 6, u = t & 63;
    const int l0 = leaf_ids[16 * b + 2 * g];
    const int l1 = leaf_ids[16 * b + 2 * g + 1];
    const float4* s0 = (const float4*)(emb + (size_t)l0 * 1024);
    const float4* s1 = (const float4*)(emb + (size_t)l1 * 1024);
#pragma unroll
    for (int q = 0; q < 4; ++q) {
      const int e4 = u + 64 * q;
      const int e = 4 * e4;
      const int i = e >> 5, j = e & 31;
      float4 a = s0[e4];
      float4 c = s1[e4];
      a.x = frelu(a.x); a.y = frelu(a.y); a.z = frelu(a.z); a.w = frelu(a.w);
      c.x = frelu(c.x); c.y = frelu(c.y); c.z = frelu(c.z); c.w = frelu(c.w);
      float* d = A + g * NS + i * 33 + j;
      d[0] = a.x + c.x; d[1] = a.y + c.y; d[2] = a.z + c.z; d[3] = a.w + c.w;
    }
  }
  __syncthreads();
  {
    const int offs1[4] = {0, 2048, 3072, 3584};
    run4(emb, bias, internal_ids, b, offs1, A, B);
  }
  {  // write root node compact; release flag1[b]
    float4* o4 = (float4*)(node256 + (size_t)b * 1024);
    for (int e4 = t; e4 < 256; e4 += 512) {
      const int e = 4 * e4;
      const float* s = B + (e >> 5) * 33 + (e & 31);
      o4[e4] = make_float4(s[0], s[1], s[2], s[3]);
    }
    __syncthreads();  // per-wave vmcnt drained -> all block stores complete
    if (t == 0)
      __hip_atomic_store(flag1 + b, MAGICV, __ATOMIC_RELEASE,
                         __HIP_MEMORY_SCOPE_AGENT);
  }
  if (b >= 16) return;

  // ================= Phase 2: blocks 0..15 =================
  if (t < 16) {
    const unsigned int* f = flag1 + 16 * b + t;
    while (__hip_atomic_load(f, __ATOMIC_ACQUIRE, __HIP_MEMORY_SCOPE_AGENT) !=
           MAGICV)
      __builtin_amdgcn_s_sleep(1);
  }
  __syncthreads();
  {  // stage: A[g] = node256[16b+2g] + node256[16b+2g+1] (agent-scope loads)
    const int g = t >> 6, u = t & 63;
    const float* s0 = node256 + (size_t)(16 * b + 2 * g) * 1024;
    const float* s1 = s0 + 1024;
#pragma unroll
    for (int q = 0; q < 4; ++q) {
      const int e = 4 * (u + 64 * q);
      const int i = e >> 5, j = e & 31;
      float* d = A + g * NS + i * 33 + j;
      d[0] = agload(s0 + e + 0) + agload(s1 + e + 0);
      d[1] = agload(s0 + e + 1) + agload(s1 + e + 1);
      d[2] = agload(s0 + e + 2) + agload(s1 + e + 2);
      d[3] = agload(s0 + e + 3) + agload(s1 + e + 3);
    }
  }
  __syncthreads();
  {
    const int offs2[4] = {3840, 3968, 4032, 4064};
    run4(emb, bias, internal_ids, b, offs2, A, B);
  }
  {
    float4* o4 = (float4*)(node16 + (size_t)b * 1024);
    for (int e4 = t; e4 < 256; e4 += 512) {
      const int e = 4 * e4;
      const float* s = B + (e >> 5) * 33 + (e & 31);
      o4[e4] = make_float4(s[0], s[1], s[2], s[3]);
    }
    __syncthreads();
    if (t == 0)
      __hip_atomic_store(flag2 + b, MAGICV, __ATOMIC_RELEASE,
                         __HIP_MEMORY_SCOPE_AGENT);
  }
  if (b >= 1) return;

  // ================= Phase 3: block 0 =================
  if (t < 16) {
    const unsigned int* f = flag2 + t;
    while (__hip_atomic_load(f, __ATOMIC_ACQUIRE, __HIP_MEMORY_SCOPE_AGENT) !=
           MAGICV)
      __builtin_amdgcn_s_sleep(1);
  }
  __syncthreads();
  {  // stage from node16
    const int g = t >> 6, u = t & 63;
    const float* s0 = node16 + (size_t)(2 * g) * 1024;
    const float* s1 = s0 + 1024;
#pragma unroll
    for (int q = 0; q < 4; ++q) {
      const int e = 4 * (u + 64 * q);
      const int i = e >> 5, j = e & 31;
      float* d = A + g * NS + i * 33 + j;
      d[0] = agload(s0 + e + 0) + agload(s1 + e + 0);
      d[1] = agload(s0 + e + 1) + agload(s1 + e + 1);
      d[2] = agload(s0 + e + 2) + agload(s1 + e + 2);
      d[3] = agload(s0 + e + 3) + agload(s1 + e + 3);
    }
  }
  __syncthreads();
  {
    const int offs3[4] = {4080, 4088, 4092, 4094};
    run4(emb, bias, internal_ids, 0, offs3, A, B);
  }
  // head on B[0] (padded): logits[l] = projb[l] + sum_e cur_flat[e]*projW[l][e]
  {
    float p0 = 0.f, p1 = 0.f;
#pragma unroll
    for (int r = 0; r < 2; ++r) {
      const int e = t + 512 * r;
      const float c = B[(e >> 5) * 33 + (e & 31)];
      p0 += c * projW[e];
      p1 += c * projW[1024 + e];
    }
#pragma unroll
    for (int off = 32; off; off >>= 1) {
      p0 += __shfl_down(p0, off);
      p1 += __shfl_down(p1, off);
    }
    if ((t & 63) == 0) { red[t >> 6] = p0; red[8 + (t >> 6)] = p1; }
    __syncthreads();
    if (t == 0) {
      float l0 = projb[0], l1 = projb[1];
#pragma unroll
      for (int q = 0; q < 8; ++q) { l0 += red[q]; l1 += red[8 + q]; }
      const float mx = fmaxf(l0, l1);
      const float lse = mx + logf(expf(l0 - mx) + expf(l1 - mx));
      const int lab = *label_ptr;
      out[0] = (l1 > l0) ? 1.f : 0.f;  // argmax (ties -> 0, matches np)
      out[1] = lse - (lab ? l1 : l0);  // -log_softmax[label]
    }
  }
}

extern "C" void kernel_launch(void* const* d_in, const int* in_sizes, int n_in,
                              void* d_out, int out_size, void* d_ws, size_t ws_size,
                              hipStream_t stream) {
  const float* emb = (const float*)d_in[0];
  const float* bias = (const float*)d_in[1];
  const float* projW = (const float*)d_in[2];
  const float* projb = (const float*)d_in[3];
  const int* leaf_ids = (const int*)d_in[4];
  const int* internal_ids = (const int*)d_in[5];
  const int* label = (const int*)d_in[6];
  float* out = (float*)d_out;

  float* node256 = (float*)d_ws;                         // 256 x 4 KB = 1 MB
  float* node16 = node256 + (size_t)256 * 1024;          // 16 x 4 KB = 64 KB
  unsigned int* flag1 = (unsigned int*)((char*)d_ws + (2u << 20));  // 1 KB
  unsigned int* flag2 = flag1 + 1024;

  tree_kernel<<<256, 512, 0, stream>>>(emb, bias, projW, projb, leaf_ids,
                                       internal_ids, label, node256, node16,
                                       flag1, flag2, out);
}